// Round 13
// baseline (412.469 us; speedup 1.0000x reference)
//
#include <hip/hip_runtime.h>

typedef unsigned int u32;
typedef unsigned short u16;
#define LN_EPS 1e-5f

typedef __attribute__((ext_vector_type(8))) short short8v;  // 8 bf16 (4 VGPRs)
typedef __attribute__((ext_vector_type(4))) float f32x4;

#define MFMA(acc, a, b) acc = __builtin_amdgcn_mfma_f32_16x16x32_bf16(a, b, acc, 0, 0, 0)

// ---------- helpers ----------
__device__ __forceinline__ float wave_sum(float v){
  #pragma unroll
  for (int o = 32; o > 0; o >>= 1) v += __shfl_xor(v, o, 64);
  return v;
}
__device__ __forceinline__ float mishf(float v){
  float t = __expf(v);
  float u = t*t + 2.f*t;
  return v * (1.f - 2.f/(u + 2.f));
}
__device__ __forceinline__ float bf2f(u16 h){
  return __uint_as_float(((u32)h) << 16);
}
// split fp32 into bf16 hi (round-half-up) + bf16 lo (trunc): x ~= hi+lo, err ~2^-17|x|
__device__ __forceinline__ u32 pack_split(float x){
  u32 u = __float_as_uint(x);
  u32 h = (u + 0x8000u) & 0xffff0000u;
  float lf = x - __uint_as_float(h);
  return h | (__float_as_uint(lf) >> 16);   // hi in top16, lo in low16
}
__device__ __forceinline__ void split_pair(float x0, float x1, u32& hw, u32& lw){
  u32 u0 = __float_as_uint(x0), u1 = __float_as_uint(x1);
  u32 h0 = (u0 + 0x8000u) & 0xffff0000u;
  u32 h1 = (u1 + 0x8000u) & 0xffff0000u;
  float l0 = x0 - __uint_as_float(h0);
  float l1 = x1 - __uint_as_float(h1);
  hw = (h0 >> 16) | h1;
  lw = (__float_as_uint(l0) >> 16) | (__float_as_uint(l1) & 0xffff0000u);
}
__device__ __forceinline__ void split8v(f32x4 a, f32x4 b, short8v& hi, short8v& lo){
  union { short8v v; u32 w[4]; } H, L;
  split_pair(a[0], a[1], H.w[0], L.w[0]);
  split_pair(a[2], a[3], H.w[1], L.w[1]);
  split_pair(b[0], b[1], H.w[2], L.w[2]);
  split_pair(b[2], b[3], H.w[3], L.w[3]);
  hi = H.v; lo = L.v;
}
__device__ __forceinline__ void unpack8(uint4 q0, uint4 q1, short8v& hi, short8v& lo){
  union { short8v v; u32 w[4]; } H, L;
  H.w[0] = (q0.x >> 16) | (q0.y & 0xffff0000u);
  L.w[0] = (q0.x & 0xffffu) | (q0.y << 16);
  H.w[1] = (q0.z >> 16) | (q0.w & 0xffff0000u);
  L.w[1] = (q0.z & 0xffffu) | (q0.w << 16);
  H.w[2] = (q1.x >> 16) | (q1.y & 0xffff0000u);
  L.w[2] = (q1.x & 0xffffu) | (q1.y << 16);
  H.w[3] = (q1.z >> 16) | (q1.w & 0xffff0000u);
  L.w[3] = (q1.z & 0xffffu) | (q1.w << 16);
  hi = H.v; lo = L.v;
}

// ---------- merged setup: ONE launch ----------
// bid 0..119  : per-seq LN -> planes (global + LDS stash) -> XP GEMM
//               (B-frags built inline from Wg: r9-proven path; no cross-block dep)
// bid 120..247: proj_W -> bf16 hi/lo B-fragment buffer (for k_pair)
// bid 248..503: W1 -> k-major packed for coalesced MLP
__global__ __launch_bounds__(256) void k_setup_all(
    const float* __restrict__ sup, const float* __restrict__ qry,
    const float* __restrict__ lng, const float* __restrict__ lnb,
    const float* __restrict__ Wg,  const float* __restrict__ W1,
    u16* __restrict__ SHI, u16* __restrict__ SLO,
    u16* __restrict__ QHI, u16* __restrict__ QLO,
    u16* __restrict__ WHI, u16* __restrict__ WLO,
    float* __restrict__ W1T2,
    float* __restrict__ XPS, float* __restrict__ XPQ)
{
  const int bid = blockIdx.x, t = threadIdx.x;

  if (bid < 120){
    __shared__ u16 LH[16384];            // [64][256] LN hi plane (32 KB)
    __shared__ u16 LL[16384];            // [64][256] LN lo plane (32 KB)
    const int seq = bid;
    const float* src; u16 *dh, *dl; float* xout;
    if (seq < 20){
      src = sup + (size_t)seq*16384;
      dh = SHI + (size_t)seq*16384; dl = SLO + (size_t)seq*16384;
      xout = XPS + (size_t)seq*16384;
    } else {
      src = qry + (size_t)(seq-20)*16384;
      dh = QHI + (size_t)(seq-20)*16384; dl = QLO + (size_t)(seq-20)*16384;
      xout = XPQ + (size_t)(seq-20)*16384;
    }
    const int w = t >> 6, lane = t & 63;

    // ---- LN -> global planes + LDS stash (identical quantization to r7 path) ----
    {
      float4 g4 = *(const float4*)(lng + lane*4);
      float4 b4 = *(const float4*)(lnb + lane*4);
      for (int r = w; r < 64; r += 4){
        float4 x = *(const float4*)(src + r*256 + lane*4);
        float s  = wave_sum(x.x + x.y + x.z + x.w);
        float sq = wave_sum(x.x*x.x + x.y*x.y + x.z*x.z + x.w*x.w);
        float mu = s*(1.f/256.f);
        float rstd = 1.f/sqrtf(sq*(1.f/256.f) - mu*mu + LN_EPS);
        float y0 = (x.x - mu)*rstd*g4.x + b4.x;
        float y1 = (x.y - mu)*rstd*g4.y + b4.y;
        float y2 = (x.z - mu)*rstd*g4.z + b4.z;
        float y3 = (x.w - mu)*rstd*g4.w + b4.w;
        u32 p0 = pack_split(y0), p1 = pack_split(y1), p2 = pack_split(y2), p3 = pack_split(y3);
        ushort4 hv = make_ushort4((u16)(p0>>16),(u16)(p1>>16),(u16)(p2>>16),(u16)(p3>>16));
        ushort4 lv = make_ushort4((u16)(p0&0xffffu),(u16)(p1&0xffffu),(u16)(p2&0xffffu),(u16)(p3&0xffffu));
        *(ushort4*)(dh + r*256 + lane*4) = hv;
        *(ushort4*)(dl + r*256 + lane*4) = lv;
        *(ushort4*)(LH + r*256 + lane*4) = hv;
        *(ushort4*)(LL + r*256 + lane*4) = lv;
      }
    }
    __syncthreads();

    // ---- XP = x_ln @ W[:,0:256]^T (A-frags from LDS, B-frags inline from Wg) ----
    const int l = lane, l15 = l & 15, l4 = l >> 4;
    const int Mg = w >> 1, Ng = w & 1;
    f32x4 acc[2][8];
    #pragma unroll
    for (int i = 0; i < 2; i++)
      #pragma unroll
      for (int j = 0; j < 8; j++){ acc[i][j][0]=0.f; acc[i][j][1]=0.f; acc[i][j][2]=0.f; acc[i][j][3]=0.f; }

    for (int ks = 0; ks < 8; ks++){
      short8v ah[2], al[2];
      #pragma unroll
      for (int mt = 0; mt < 2; mt++){
        const int ro = (Mg*32 + mt*16 + l15)*256 + ks*32 + l4*8;
        ah[mt] = *(const short8v*)(LH + ro);
        al[mt] = *(const short8v*)(LL + ro);
      }
      #pragma unroll
      for (int nt = 0; nt < 8; nt++){
        const float* wsrc = Wg + (size_t)((Ng*8 + nt)*16 + l15)*1024 + ks*32 + l4*8;
        float4 xa = *(const float4*)wsrc;
        float4 xb = *(const float4*)(wsrc + 4);
        f32x4 fa, fb;
        fa[0]=xa.x; fa[1]=xa.y; fa[2]=xa.z; fa[3]=xa.w;
        fb[0]=xb.x; fb[1]=xb.y; fb[2]=xb.z; fb[3]=xb.w;
        short8v bh, bl;
        split8v(fa, fb, bh, bl);
        #pragma unroll
        for (int mt = 0; mt < 2; mt++){
          MFMA(acc[mt][nt], ah[mt], bh);
          MFMA(acc[mt][nt], ah[mt], bl);
          MFMA(acc[mt][nt], al[mt], bh);
        }
      }
    }
    #pragma unroll
    for (int mt = 0; mt < 2; mt++)
      #pragma unroll
      for (int nt = 0; nt < 8; nt++)
        #pragma unroll
        for (int r = 0; r < 4; r++)
          xout[(Mg*32 + mt*16 + l4*4 + r)*256 + Ng*128 + nt*16 + l15] = acc[mt][nt][r];

  } else if (bid < 248){
    // ---- proj_W -> bf16 hi/lo, B-fragment order ----
    // frag: [kstep 0..31][ntile 0..15][lane 0..63][e 0..7]
    const int gid = (bid-120)*256 + t;               // 0..32767
    const int ks = gid >> 10, rem = gid & 1023, nt = rem >> 6, l = rem & 63;
    const int n  = nt*16 + (l & 15);
    const int k0 = ks*32 + (l >> 4)*8;
    const float* src = Wg + n*1024 + k0;
    float4 xa = *(const float4*)src;
    float4 xb = *(const float4*)(src + 4);
    f32x4 fa, fb;
    fa[0]=xa.x; fa[1]=xa.y; fa[2]=xa.z; fa[3]=xa.w;
    fb[0]=xb.x; fb[1]=xb.y; fb[2]=xb.z; fb[3]=xb.w;
    short8v hi, lo;
    split8v(fa, fb, hi, lo);
    *(short8v*)(WHI + (size_t)gid*8) = hi;
    *(short8v*)(WLO + (size_t)gid*8) = lo;
  } else {
    // ---- W1 -> k-major packed for coalesced MLP ----
    const int gid = (bid-248)*256 + t;               // 0..65535
    const int kb = gid >> 8, n = gid & 255;
    float4 v = *(const float4*)(W1 + n*1024 + kb*4);
    *(float4*)(W1T2 + kb*1024 + n*4) = v;
  }
}

// ---- proj W-pipeline macros: half-group (4 ntiles) stages, double-buffered ----
#define WLH(BUF, C, H) { const int base_ = (((C)*8 + ch)*16 + Ng*8 + (H)*4)*512 + l*8; \
  _Pragma("unroll") for (int j_ = 0; j_ < 4; j_++){ \
    BUF[j_*2]   = *(const short8v*)(WHI + base_ + j_*512); \
    BUF[j_*2+1] = *(const short8v*)(WLO + base_ + j_*512); } }
#define WMH(BUF, G, H) { _Pragma("unroll") for (int j_ = 0; j_ < 4; j_++){ \
  MFMA(acc[0][(H)*4+j_], fh[G][0], BUF[j_*2]); \
  MFMA(acc[0][(H)*4+j_], fh[G][0], BUF[j_*2+1]); \
  MFMA(acc[0][(H)*4+j_], fl[G][0], BUF[j_*2]); \
  MFMA(acc[1][(H)*4+j_], fh[G][1], BUF[j_*2]); \
  MFMA(acc[1][(H)*4+j_], fh[G][1], BUF[j_*2+1]); \
  MFMA(acc[1][(H)*4+j_], fl[G][1], BUF[j_*2]); } }

// ---------- main: one (query,support) pair per block ----------
// LDS 78,400 B -> 2 blocks/CU. ONE barrier per ch (AOc double-buffered). First W
// batch prefetched above AO phase. Session-best configuration: 2 waves/SIMD,
// 128 VGPR + 64 AGPR, zero inner-loop spill. Occupancy increases (r10/r11) both
// spill catastrophically; work removal (r9) regressed (latency-paced loop).
__global__ __launch_bounds__(256, 2) void k_pair15(
    const u16* __restrict__ SHI, const u16* __restrict__ SLO,
    const u16* __restrict__ QHI, const u16* __restrict__ QLO,
    const u16* __restrict__ WHI, const u16* __restrict__ WLO,
    const float* __restrict__ XPS, const float* __restrict__ XPQ,
    const float* __restrict__ W1T2,
    const float* __restrict__ pbias,
    const float* __restrict__ ln2g, const float* __restrict__ ln2b,
    const float* __restrict__ b1,
    const float* __restrict__ W2,  const float* __restrict__ b2,
    const float* __restrict__ W3,  const float* __restrict__ b3,
    float* __restrict__ logits)
{
  __shared__ float SM[19600];            // 78,400 B
  float* S0  = SM;                       // [64][68] f32 scores — persists both sides
  u16*   OcT = (u16*)(SM + 4352);        // [2 buf][2 pl][32][80] u16 (10,240 u16)
  float* AOc = SM + 9472;                // [2 buf][64][36] f32 (4,608)
  u32*   P   = (u32*)(SM + 14080);       // [64][68] packed hi|lo (pool partials reuse)
  float* cat = SM + 18432;               // [1024]
  float* smx = SM + 19456;
  float* smi = SM + 19520;
  float* red = SM + 19584;
  float* stat= SM + 19592;
  float* mred= SM + 19594;

  // XCD-aware swizzle: 1000 % 8 == 0 -> bijective chunked map.
  const int m = (blockIdx.x & 7)*125 + (blockIdx.x >> 3);
  const int b = m / 500, rr = m % 500, nq = rr / 10, n_ = rr % 10;
  const u16* Sh = SHI + (size_t)(b*10 + n_) * 16384;
  const u16* Sl = SLO + (size_t)(b*10 + n_) * 16384;
  const u16* Qh = QHI + (size_t)(b*50 + nq) * 16384;
  const u16* Ql = QLO + (size_t)(b*50 + nq) * 16384;
  const float* xpS = XPS + (size_t)(b*10 + n_) * 16384;
  const float* xpQ = XPQ + (size_t)(b*50 + nq) * 16384;

  const int t = threadIdx.x, w = t >> 6, l = t & 63;
  const int l15 = l & 15, l4 = l >> 4;

  // ===== attention scores S0 = Sln @ Qln^T (once; S0 stays resident) =====
  {
    f32x4 acc4[4];
    #pragma unroll
    for (int i = 0; i < 4; i++){ acc4[i][0]=0.f; acc4[i][1]=0.f; acc4[i][2]=0.f; acc4[i][3]=0.f; }
    const u16* Sa = Sh + (w*16+l15)*256 + l4*8;
    const u16* Sb = Sl + (w*16+l15)*256 + l4*8;
    short8v ah = *(const short8v*)Sa;
    short8v al = *(const short8v*)Sb;
    short8v bh[4], bl[4];
    #pragma unroll
    for (int nt = 0; nt < 4; nt++){
      bh[nt] = *(const short8v*)(Qh + (nt*16+l15)*256 + l4*8);
      bl[nt] = *(const short8v*)(Ql + (nt*16+l15)*256 + l4*8);
    }
    #pragma unroll
    for (int ch = 0; ch < 8; ch++){
      short8v nah, nal, nbh[4], nbl[4];
      if (ch < 7){
        nah = *(const short8v*)(Sa + (ch+1)*32);
        nal = *(const short8v*)(Sb + (ch+1)*32);
        #pragma unroll
        for (int nt = 0; nt < 4; nt++){
          nbh[nt] = *(const short8v*)(Qh + (nt*16+l15)*256 + (ch+1)*32 + l4*8);
          nbl[nt] = *(const short8v*)(Ql + (nt*16+l15)*256 + (ch+1)*32 + l4*8);
        }
      }
      #pragma unroll
      for (int nt = 0; nt < 4; nt++){
        MFMA(acc4[nt], ah, bh[nt]);
        MFMA(acc4[nt], ah, bl[nt]);
        MFMA(acc4[nt], al, bh[nt]);
      }
      if (ch < 7){
        ah = nah; al = nal;
        #pragma unroll
        for (int nt = 0; nt < 4; nt++){ bh[nt] = nbh[nt]; bl[nt] = nbl[nt]; }
      }
    }
    #pragma unroll
    for (int nt = 0; nt < 4; nt++)
      #pragma unroll
      for (int r = 0; r < 4; r++)
        S0[(w*16 + l4*4 + r)*68 + nt*16 + l15] = acc4[nt][r];
    __syncthreads();
  }

  // ===== softmax: fp32 from S0, write P packed hi|lo =====
  auto softmax_row = [&](){
    if (t < 64){
      float mxv = -1e30f, sm = 0.f;
      for (int k = 0; k < 64; k++) mxv = fmaxf(mxv, S0[t*68 + k]);
      for (int k = 0; k < 64; k++) sm += __expf(S0[t*68 + k] - mxv);
      smx[t] = mxv; smi[t] = 1.f/sm;
    }
    __syncthreads();
    #pragma unroll
    for (int r = 0; r < 16; r++){
      int idx = t + 256*r, ll = idx >> 6, k = idx & 63;
      P[ll*68 + k] = pack_split(__expf(S0[ll*68 + k] - smx[ll]) * smi[ll]);
    }
    __syncthreads();
  };
  auto softmax_col_T = [&](){
    if (t < 64){
      float mxv = -1e30f, sm = 0.f;
      for (int ld = 0; ld < 64; ld++) mxv = fmaxf(mxv, S0[ld*68 + t]);
      for (int ld = 0; ld < 64; ld++) sm += __expf(S0[ld*68 + t] - mxv);
      smx[t] = mxv; smi[t] = 1.f/sm;
    }
    __syncthreads();
    #pragma unroll
    for (int r = 0; r < 16; r++){         // read S0, write P (disjoint) — no race
      int idx = t + 256*r, ll = idx >> 6, k = idx & 63;
      P[k*68 + ll] = pack_split(__expf(S0[ll*68 + k] - smx[k]) * smi[k]);
    }
    __syncthreads();
  };

  // ===== one side: 1 barrier per ch, acc init from XP =====
  auto do_side = [&](const u16* Xh, const u16* Xl, const u16* Oh, const u16* Ol,
                     const float* xp, int cat_off){
    const int Mg = w >> 1, Ng = w & 1;
    f32x4 acc[2][8];
    #pragma unroll
    for (int mt = 0; mt < 2; mt++)
      #pragma unroll
      for (int nt = 0; nt < 8; nt++){
        const float* xr = xp + (Mg*32 + mt*16 + l4*4)*256 + Ng*128 + nt*16 + l15;
        acc[mt][nt][0] = xr[0];
        acc[mt][nt][1] = xr[256];
        acc[mt][nt][2] = xr[512];
        acc[mt][nt][3] = xr[768];
      }

    // ---- prime: OcT ch0 (load+write buf0), issue OcT ch1 loads ----
    short8v svh = *(const short8v*)(Oh + l*256 + w*8);
    short8v svl = *(const short8v*)(Ol + l*256 + w*8);
    #pragma unroll
    for (int e = 0; e < 8; e++){
      OcT[(w*8+e)*80 + l]        = (u16)svh[e];
      OcT[2560 + (w*8+e)*80 + l] = (u16)svl[e];
    }
    svh = *(const short8v*)(Oh + l*256 + 32 + w*8);
    svl = *(const short8v*)(Ol + l*256 + 32 + w*8);
    __syncthreads();                     // OcT[0] visible

    const int xoff = (Mg*32 + l15)*256 + l4*8;

    #pragma unroll 1
    for (int ch = 0; ch < 8; ch++){
      // ---- issue X loads + first proj-W batch (consumed after barrier) ----
      short8v xh0 = *(const short8v*)(Xh + xoff + ch*32);
      short8v xl0 = *(const short8v*)(Xl + xoff + ch*32);
      short8v xh1 = *(const short8v*)(Xh + xoff + 4096 + ch*32);
      short8v xl1 = *(const short8v*)(Xl + xoff + 4096 + ch*32);
      short8v wa[8], wb[8];
      WLH(wa, 1, 0);                     // L2 latency hides under AO MFMAs

      // ---- AO chunk = P @ O from OcT[ch&1] -> AOc[ch&1] ----
      {
        const u16* Ob = OcT + (ch&1)*5120;
        f32x4 ao0 = {0.f,0.f,0.f,0.f}, ao1 = {0.f,0.f,0.f,0.f};
        #pragma unroll
        for (int ks = 0; ks < 2; ks++){
          const u32* pp = P + (w*16 + l15)*68 + ks*32 + l4*8;
          uint4 q0 = *(const uint4*)pp;
          uint4 q1 = *(const uint4*)(pp + 4);
          short8v ph, pl; unpack8(q0, q1, ph, pl);
          const u16* ob0 = Ob + l15*80 + ks*32 + l4*8;
          const u16* ob1 = Ob + (16 + l15)*80 + ks*32 + l4*8;
          short8v bh0 = *(const short8v*)ob0;
          short8v bl0 = *(const short8v*)(ob0 + 2560);
          short8v bh1 = *(const short8v*)ob1;
          short8v bl1 = *(const short8v*)(ob1 + 2560);
          MFMA(ao0, ph, bh0); MFMA(ao0, ph, bl0); MFMA(ao0, pl, bh0);
          MFMA(ao1, ph, bh1); MFMA(ao1, ph, bl1); MFMA(ao1, pl, bh1);
        }
        float* Ad = AOc + (ch&1)*2304;
        #pragma unroll
        for (int r = 0; r < 4; r++){
          Ad[(w*16 + l4*4 + r)*36 + l15]      = ao0[r];
          Ad[(w*16 + l4*4 + r)*36 + 16 + l15] = ao1[r];
        }
      }

      // ---- stage OcT[(ch+1)&1] from regs (pre-barrier); issue ch+2 O loads ----
      if (ch < 7){
        u16* Ob1 = OcT + ((ch+1)&1)*5120;
        #pragma unroll
        for (int e = 0; e < 8; e++){
          Ob1[(w*8+e)*80 + l]        = (u16)svh[e];
          Ob1[2560 + (w*8+e)*80 + l] = (u16)svl[e];
        }
      }
      if (ch < 6){
        svh = *(const short8v*)(Oh + l*256 + (ch+2)*32 + w*8);
        svl = *(const short8v*)(Ol + l*256 + (ch+2)*32 + w*8);
      }
      __syncthreads();                   // single barrier: AOc[ch&1]+OcT[(ch+1)&1] visible

      // ---- build feature groups (a, |x-a|, x*a) from AOc[ch&1] ----
      short8v fh[3][2], fl[3][2];
      {
        const float* Ad = AOc + (ch&1)*2304;
        f32x4 xv0[2], xv1[2], av0[2], av1[2];
        #pragma unroll
        for (int mt_ = 0; mt_ < 2; mt_++){
          short8v xh = mt_ ? xh1 : xh0;
          short8v xl = mt_ ? xl1 : xl0;
          #pragma unroll
          for (int e_ = 0; e_ < 4; e_++){
            xv0[mt_][e_] = bf2f((u16)xh[e_])     + bf2f((u16)xl[e_]);
            xv1[mt_][e_] = bf2f((u16)xh[4 + e_]) + bf2f((u16)xl[4 + e_]);
          }
          const int row = Mg*32 + mt_*16 + l15;
          av0[mt_] = *(const f32x4*)(Ad + row*36 + l4*8);
          av1[mt_] = *(const f32x4*)(Ad + row*36 + l4*8 + 4);
        }
        #pragma unroll
        for (int mt_ = 0; mt_ < 2; mt_++){
          split8v(av0[mt_], av1[mt_], fh[0][mt_], fl[0][mt_]);
          f32x4 d0, d1, p0, p1;
          #pragma unroll
          for (int e_ = 0; e_ < 4; e_++){
            d0[e_] = fabsf(xv0[mt_][e_] - av0[mt_][e_]);
            d1[e_] = fabsf(xv1[mt_][e_] - av1[mt_][e_]);
            p0[e_] = xv0[mt_][e_] * av0[mt_][e_];
            p1[e_] = xv1[mt_][e_] * av1[mt_][e_];
          }
          split8v(d0, d1, fh[1][mt_], fl[1][mt_]);
          split8v(p0, p1, fh[2][mt_], fl[2][mt_]);
        }
      }

      // ---- proj: 6 half-group stages (wa preloaded), double-buffered W ----
      WLH(wb, 1, 1);
      WMH(wa, 0, 0);
      WLH(wa, 2, 0);
      WMH(wb, 0, 1);
      WLH(wb, 2, 1);
      WMH(wa, 1, 0);
      WLH(wa, 3, 0);
      WMH(wb, 1, 1);
      WLH(wb, 3, 1);
      WMH(wa, 2, 0);
      WMH(wb, 2, 1);
    }

    // ---- bias+mish+pool (max & mean over 64 rows) ----
    float* pmax2 = (float*)P;            // P dead -> [2 Mgroups][256]
    float* psum2 = pmax2 + 512;
    #pragma unroll
    for (int nt = 0; nt < 8; nt++){
      const int col = Ng*128 + nt*16 + l15;
      const float pb = pbias[col];
      float mx = -1e30f, sm = 0.f;
      #pragma unroll
      for (int mt_ = 0; mt_ < 2; mt_++)
        #pragma unroll
        for (int r = 0; r < 4; r++){
          float v = mishf(acc[mt_][nt][r] + pb);
          mx = fmaxf(mx, v); sm += v;
        }
      mx = fmaxf(mx, __shfl_xor(mx, 16, 64));
      mx = fmaxf(mx, __shfl_xor(mx, 32, 64));
      sm += __shfl_xor(sm, 16, 64);
      sm += __shfl_xor(sm, 32, 64);
      if (l4 == 0){ pmax2[Mg*256 + col] = mx; psum2[Mg*256 + col] = sm; }
    }
    __syncthreads();
    // ---- LN2 over 512 [max|mean] -> cat ----
    float v1 = fmaxf(pmax2[t], pmax2[256 + t]);
    float v2 = (psum2[t] + psum2[256 + t]) * (1.f/64.f);
    float p1 = wave_sum(v1 + v2);
    float p2 = wave_sum(v1*v1 + v2*v2);
    if (l == 0){ red[w] = p1; red[4 + w] = p2; }
    __syncthreads();
    if (t == 0){
      float s1 = red[0]+red[1]+red[2]+red[3];
      float s2 = red[4]+red[5]+red[6]+red[7];
      float mu  = s1 * (1.f/512.f);
      float var = s2 * (1.f/512.f) - mu*mu;
      stat[0] = mu; stat[1] = 1.f/sqrtf(var + LN_EPS);
    }
    __syncthreads();
    float mu = stat[0], rstd = stat[1];
    cat[cat_off + t]       = (v1 - mu)*rstd*ln2g[t]       + ln2b[t];
    cat[cat_off + 256 + t] = (v2 - mu)*rstd*ln2g[256 + t] + ln2b[256 + t];
    __syncthreads();
  };

  // ===== side S: P = rowSoftmax; x = s, other = q =====
  softmax_row();
  do_side(Sh, Sl, Qh, Ql, xpS, 512);
  // ===== side Q: P = colSoftmax^T (S0 still resident); x = q, other = s =====
  softmax_col_T();
  do_side(Qh, Ql, Sh, Sl, xpQ, 0);

  // ===== MLP (fp32, coalesced k-major W1) =====
  {
    float acc1 = 0.f;
    const float* wt = W1T2 + t*4;
    #pragma unroll 8
    for (int kb = 0; kb < 256; kb++){
      float4 wv = *(const float4*)(wt + kb*1024);
      const float* cp = &cat[kb*4];
      acc1 += cp[0]*wv.x + cp[1]*wv.y + cp[2]*wv.z + cp[3]*wv.w;
    }
    float hv = mishf(acc1 + b1[t]);
    float contrib = wave_sum(hv * W2[t]);
    if (l == 0) mred[w] = contrib;
  }
  __syncthreads();
  if (t == 0){
    float hh = mred[0] + mred[1] + mred[2] + mred[3] + b2[0];
    logits[m] = mishf(hh)*W3[0] + b3[0];
  }
}

// ---------- finalize (fp32 output) ----------
__global__ void k_final9(const float* __restrict__ logits, float* __restrict__ out){
  int t = threadIdx.x;                   // 128
  if (t < 100){
    float v[10];
    float mn = 1e30f;
    #pragma unroll
    for (int j = 0; j < 10; j++){ v[j] = logits[t*10 + j]; mn = fminf(mn, v[j]); }
    float best = -1e30f; int bi = 0;
    #pragma unroll
    for (int j = 0; j < 10; j++){ if (v[j] > best){ best = v[j]; bi = j; } }
    #pragma unroll
    for (int j = 0; j < 10; j++) out[t*11 + j] = v[j];
    out[t*11 + 10] = mn - 1.f;
    out[1100 + t] = (float)bi;
  }
}

// ---------- launcher ----------
extern "C" void kernel_launch(void* const* d_in, const int* in_sizes, int n_in,
                              void* d_out, int out_size, void* d_ws, size_t ws_size,
                              hipStream_t stream){
  (void)in_sizes; (void)n_in; (void)out_size; (void)ws_size;
  const float* support = (const float*)d_in[0];
  const float* query   = (const float*)d_in[1];
  const float* ln_g    = (const float*)d_in[2];
  const float* ln_b    = (const float*)d_in[3];
  const float* ln2_g   = (const float*)d_in[4];
  const float* ln2_b   = (const float*)d_in[5];
  const float* proj_W  = (const float*)d_in[6];
  const float* proj_b  = (const float*)d_in[7];
  const float* W1      = (const float*)d_in[8];
  const float* b1      = (const float*)d_in[9];
  const float* W2      = (const float*)d_in[10];
  const float* b2      = (const float*)d_in[11];
  const float* W3      = (const float*)d_in[12];
  const float* b3      = (const float*)d_in[13];

  // workspace layout: the r7-proven 17,829,888 B footprint (unchanged).
  char* wsb = (char*)d_ws;
  float* logits = (float*)wsb;                           // 4 KB
  u16* SHI = (u16*)(wsb + 4096);                         // 20*16384*2  = 640 KB
  u16* SLO = SHI + (size_t)20*16384;
  u16* QHI = SLO + (size_t)20*16384;                     // 100*16384*2 = 3.2 MB
  u16* QLO = QHI + (size_t)100*16384;
  u16* WHI = QLO + (size_t)100*16384;                    // 512 KB (frag order)
  u16* WLO = WHI + (size_t)262144;
  float* XPS  = (float*)(WLO + (size_t)262144);          // 20*16384*4  = 1.31 MB
  float* XPQ  = XPS + (size_t)20*16384;                  // 100*16384*4 = 6.55 MB
  float* W1T2 = XPQ + (size_t)100*16384;                 // 1 MB

  k_setup_all<<<dim3(504), dim3(256), 0, stream>>>(support, query, ln_g, ln_b,
                                                   proj_W, W1,
                                                   SHI, SLO, QHI, QLO, WHI, WLO,
                                                   W1T2, XPS, XPQ);
  k_pair15<<<dim3(1000), dim3(256), 0, stream>>>(SHI, SLO, QHI, QLO, WHI, WLO,
                                                 XPS, XPQ, W1T2,
                                                 proj_b, ln2_g, ln2_b,
                                                 b1, W2, b2, W3, b3, logits);
  k_final9<<<dim3(1), dim3(128), 0, stream>>>(logits, (float*)d_out);
}

// Round 14
// 393.856 us; speedup vs baseline: 1.0473x; 1.0473x over previous
//
#include <hip/hip_runtime.h>

typedef unsigned int u32;
typedef unsigned short u16;
#define LN_EPS 1e-5f

typedef __attribute__((ext_vector_type(8))) short short8v;  // 8 bf16 (4 VGPRs)
typedef __attribute__((ext_vector_type(4))) float f32x4;

#define MFMA(acc, a, b) acc = __builtin_amdgcn_mfma_f32_16x16x32_bf16(a, b, acc, 0, 0, 0)

// ---------- helpers ----------
__device__ __forceinline__ float wave_sum(float v){
  #pragma unroll
  for (int o = 32; o > 0; o >>= 1) v += __shfl_xor(v, o, 64);
  return v;
}
__device__ __forceinline__ float mishf(float v){
  float t = __expf(v);
  float u = t*t + 2.f*t;
  return v * (1.f - 2.f/(u + 2.f));
}
__device__ __forceinline__ float bf2f(u16 h){
  return __uint_as_float(((u32)h) << 16);
}
// split fp32 into bf16 hi (round-half-up) + bf16 lo (trunc): x ~= hi+lo, err ~2^-17|x|
__device__ __forceinline__ u32 pack_split(float x){
  u32 u = __float_as_uint(x);
  u32 h = (u + 0x8000u) & 0xffff0000u;
  float lf = x - __uint_as_float(h);
  return h | (__float_as_uint(lf) >> 16);   // hi in top16, lo in low16
}
__device__ __forceinline__ void split_pair(float x0, float x1, u32& hw, u32& lw){
  u32 u0 = __float_as_uint(x0), u1 = __float_as_uint(x1);
  u32 h0 = (u0 + 0x8000u) & 0xffff0000u;
  u32 h1 = (u1 + 0x8000u) & 0xffff0000u;
  float l0 = x0 - __uint_as_float(h0);
  float l1 = x1 - __uint_as_float(h1);
  hw = (h0 >> 16) | h1;
  lw = (__float_as_uint(l0) >> 16) | (__float_as_uint(l1) & 0xffff0000u);
}
__device__ __forceinline__ void split8v(f32x4 a, f32x4 b, short8v& hi, short8v& lo){
  union { short8v v; u32 w[4]; } H, L;
  split_pair(a[0], a[1], H.w[0], L.w[0]);
  split_pair(a[2], a[3], H.w[1], L.w[1]);
  split_pair(b[0], b[1], H.w[2], L.w[2]);
  split_pair(b[2], b[3], H.w[3], L.w[3]);
  hi = H.v; lo = L.v;
}
__device__ __forceinline__ void unpack8(uint4 q0, uint4 q1, short8v& hi, short8v& lo){
  union { short8v v; u32 w[4]; } H, L;
  H.w[0] = (q0.x >> 16) | (q0.y & 0xffff0000u);
  L.w[0] = (q0.x & 0xffffu) | (q0.y << 16);
  H.w[1] = (q0.z >> 16) | (q0.w & 0xffff0000u);
  L.w[1] = (q0.z & 0xffffu) | (q0.w << 16);
  H.w[2] = (q1.x >> 16) | (q1.y & 0xffff0000u);
  L.w[2] = (q1.x & 0xffffu) | (q1.y << 16);
  H.w[3] = (q1.z >> 16) | (q1.w & 0xffff0000u);
  L.w[3] = (q1.z & 0xffffu) | (q1.w << 16);
  hi = H.v; lo = L.v;
}

// ---------- setup A: LN planes + W frags + W1 transpose (independent writes) ----------
__global__ void k_setup_A(const float* __restrict__ sup, const float* __restrict__ qry,
                          const float* __restrict__ lng, const float* __restrict__ lnb,
                          const float* __restrict__ Wg,  const float* __restrict__ W1,
                          u16* __restrict__ SHI, u16* __restrict__ SLO,
                          u16* __restrict__ QHI, u16* __restrict__ QLO,
                          u16* __restrict__ WHI, u16* __restrict__ WLO,
                          float* __restrict__ W1T2)
{
  const int bid = blockIdx.x, t = threadIdx.x;

  if (bid < 120){
    // ---- LayerNorm S/Q -> bf16 hi/lo planes ----
    const int seq = bid;
    const float* src; u16 *dh, *dl;
    if (seq < 20){
      src = sup + (size_t)seq*16384;
      dh = SHI + (size_t)seq*16384; dl = SLO + (size_t)seq*16384;
    } else {
      src = qry + (size_t)(seq-20)*16384;
      dh = QHI + (size_t)(seq-20)*16384; dl = QLO + (size_t)(seq-20)*16384;
    }
    const int w = t >> 6, lane = t & 63;
    float4 g4 = *(const float4*)(lng + lane*4);
    float4 b4 = *(const float4*)(lnb + lane*4);
    for (int r = w; r < 64; r += 4){
      float4 x = *(const float4*)(src + r*256 + lane*4);
      float s  = wave_sum(x.x + x.y + x.z + x.w);
      float sq = wave_sum(x.x*x.x + x.y*x.y + x.z*x.z + x.w*x.w);
      float mu = s*(1.f/256.f);
      float rstd = 1.f/sqrtf(sq*(1.f/256.f) - mu*mu + LN_EPS);
      float y0 = (x.x - mu)*rstd*g4.x + b4.x;
      float y1 = (x.y - mu)*rstd*g4.y + b4.y;
      float y2 = (x.z - mu)*rstd*g4.z + b4.z;
      float y3 = (x.w - mu)*rstd*g4.w + b4.w;
      u32 p0 = pack_split(y0), p1 = pack_split(y1), p2 = pack_split(y2), p3 = pack_split(y3);
      ushort4 hv = make_ushort4((u16)(p0>>16),(u16)(p1>>16),(u16)(p2>>16),(u16)(p3>>16));
      ushort4 lv = make_ushort4((u16)(p0&0xffffu),(u16)(p1&0xffffu),(u16)(p2&0xffffu),(u16)(p3&0xffffu));
      *(ushort4*)(dh + r*256 + lane*4) = hv;
      *(ushort4*)(dl + r*256 + lane*4) = lv;
    }
  } else if (bid < 248){
    // ---- proj_W -> bf16 hi/lo, B-fragment order ----
    // frag: [kstep 0..31][ntile 0..15][lane 0..63][e 0..7]
    const int gid = (bid-120)*256 + t;               // 0..32767
    const int ks = gid >> 10, rem = gid & 1023, nt = rem >> 6, l = rem & 63;
    const int n  = nt*16 + (l & 15);
    const int k0 = ks*32 + (l >> 4)*8;
    const float* src = Wg + n*1024 + k0;
    float4 xa = *(const float4*)src;
    float4 xb = *(const float4*)(src + 4);
    f32x4 fa, fb;
    fa[0]=xa.x; fa[1]=xa.y; fa[2]=xa.z; fa[3]=xa.w;
    fb[0]=xb.x; fb[1]=xb.y; fb[2]=xb.z; fb[3]=xb.w;
    short8v hi, lo;
    split8v(fa, fb, hi, lo);
    *(short8v*)(WHI + (size_t)gid*8) = hi;
    *(short8v*)(WLO + (size_t)gid*8) = lo;
  } else {
    // ---- W1 -> k-major packed for coalesced MLP ----
    const int gid = (bid-248)*256 + t;               // 0..65535
    const int kb = gid >> 8, n = gid & 255;
    float4 v = *(const float4*)(W1 + n*1024 + kb*4);
    *(float4*)(W1T2 + kb*1024 + n*4) = v;
  }
}

// ---------- setup B: XP[seq] = x_ln @ W[:,0:256]^T (pair-independent quarter) ----------
__global__ __launch_bounds__(256) void k_setup_xp(
    const u16* __restrict__ SHI, const u16* __restrict__ SLO,
    const u16* __restrict__ QHI, const u16* __restrict__ QLO,
    const u16* __restrict__ WHI, const u16* __restrict__ WLO,
    float* __restrict__ XPS, float* __restrict__ XPQ)
{
  const int seq = blockIdx.x;   // 0..19 support, 20..119 query
  const u16 *Xh, *Xl; float* out;
  if (seq < 20){
    Xh = SHI + (size_t)seq*16384; Xl = SLO + (size_t)seq*16384;
    out = XPS + (size_t)seq*16384;
  } else {
    Xh = QHI + (size_t)(seq-20)*16384; Xl = QLO + (size_t)(seq-20)*16384;
    out = XPQ + (size_t)(seq-20)*16384;
  }
  const int t = threadIdx.x, w = t >> 6, l = t & 63;
  const int l15 = l & 15, l4 = l >> 4;
  const int Mg = w >> 1, Ng = w & 1;

  f32x4 acc[2][8];
  #pragma unroll
  for (int i = 0; i < 2; i++)
    #pragma unroll
    for (int j = 0; j < 8; j++){ acc[i][j][0]=0.f; acc[i][j][1]=0.f; acc[i][j][2]=0.f; acc[i][j][3]=0.f; }

  for (int ks = 0; ks < 8; ks++){
    short8v ah[2], al[2];
    #pragma unroll
    for (int mt = 0; mt < 2; mt++){
      const int ro = (Mg*32 + mt*16 + l15)*256 + ks*32 + l4*8;
      ah[mt] = *(const short8v*)(Xh + ro);
      al[mt] = *(const short8v*)(Xl + ro);
    }
    #pragma unroll
    for (int nt = 0; nt < 8; nt++){
      const int fo = (ks*16 + Ng*8 + nt)*512 + l*8;
      short8v bh = *(const short8v*)(WHI + fo);
      short8v bl = *(const short8v*)(WLO + fo);
      #pragma unroll
      for (int mt = 0; mt < 2; mt++){
        MFMA(acc[mt][nt], ah[mt], bh);
        MFMA(acc[mt][nt], ah[mt], bl);
        MFMA(acc[mt][nt], al[mt], bh);
      }
    }
  }
  #pragma unroll
  for (int mt = 0; mt < 2; mt++)
    #pragma unroll
    for (int nt = 0; nt < 8; nt++)
      #pragma unroll
      for (int r = 0; r < 4; r++)
        out[(Mg*32 + mt*16 + l4*4 + r)*256 + Ng*128 + nt*16 + l15] = acc[mt][nt][r];
}

// ---- proj W-pipeline macros: half-group (4 ntiles) stages, double-buffered ----
#define WLH(BUF, C, H) { const int base_ = (((C)*8 + ch)*16 + Ng*8 + (H)*4)*512 + l*8; \
  _Pragma("unroll") for (int j_ = 0; j_ < 4; j_++){ \
    BUF[j_*2]   = *(const short8v*)(WHI + base_ + j_*512); \
    BUF[j_*2+1] = *(const short8v*)(WLO + base_ + j_*512); } }
#define WMH(BUF, G, H) { _Pragma("unroll") for (int j_ = 0; j_ < 4; j_++){ \
  MFMA(acc[0][(H)*4+j_], fh[G][0], BUF[j_*2]); \
  MFMA(acc[0][(H)*4+j_], fh[G][0], BUF[j_*2+1]); \
  MFMA(acc[0][(H)*4+j_], fl[G][0], BUF[j_*2]); \
  MFMA(acc[1][(H)*4+j_], fh[G][1], BUF[j_*2]); \
  MFMA(acc[1][(H)*4+j_], fh[G][1], BUF[j_*2+1]); \
  MFMA(acc[1][(H)*4+j_], fl[G][1], BUF[j_*2]); } }

// ---------- main: one (query,support) pair per block ----------
// LDS 78,400 B -> 2 blocks/CU. ONE barrier per ch (AOc double-buffered). First W
// batch prefetched above AO phase. Session-best configuration: 2 waves/SIMD,
// 128 VGPR + 64 AGPR, zero inner-loop spill. Occupancy increases (r10/r11) both
// spill catastrophically; work removal (r9) regressed; setup merge (r13)
// regressed. Structural optimum of this decomposition.
__global__ __launch_bounds__(256, 2) void k_pair15(
    const u16* __restrict__ SHI, const u16* __restrict__ SLO,
    const u16* __restrict__ QHI, const u16* __restrict__ QLO,
    const u16* __restrict__ WHI, const u16* __restrict__ WLO,
    const float* __restrict__ XPS, const float* __restrict__ XPQ,
    const float* __restrict__ W1T2,
    const float* __restrict__ pbias,
    const float* __restrict__ ln2g, const float* __restrict__ ln2b,
    const float* __restrict__ b1,
    const float* __restrict__ W2,  const float* __restrict__ b2,
    const float* __restrict__ W3,  const float* __restrict__ b3,
    float* __restrict__ logits)
{
  __shared__ float SM[19600];            // 78,400 B
  float* S0  = SM;                       // [64][68] f32 scores — persists both sides
  u16*   OcT = (u16*)(SM + 4352);        // [2 buf][2 pl][32][80] u16 (10,240 u16)
  float* AOc = SM + 9472;                // [2 buf][64][36] f32 (4,608)
  u32*   P   = (u32*)(SM + 14080);       // [64][68] packed hi|lo (pool partials reuse)
  float* cat = SM + 18432;               // [1024]
  float* smx = SM + 19456;
  float* smi = SM + 19520;
  float* red = SM + 19584;
  float* stat= SM + 19592;
  float* mred= SM + 19594;

  // XCD-aware swizzle: 1000 % 8 == 0 -> bijective chunked map.
  const int m = (blockIdx.x & 7)*125 + (blockIdx.x >> 3);
  const int b = m / 500, rr = m % 500, nq = rr / 10, n_ = rr % 10;
  const u16* Sh = SHI + (size_t)(b*10 + n_) * 16384;
  const u16* Sl = SLO + (size_t)(b*10 + n_) * 16384;
  const u16* Qh = QHI + (size_t)(b*50 + nq) * 16384;
  const u16* Ql = QLO + (size_t)(b*50 + nq) * 16384;
  const float* xpS = XPS + (size_t)(b*10 + n_) * 16384;
  const float* xpQ = XPQ + (size_t)(b*50 + nq) * 16384;

  const int t = threadIdx.x, w = t >> 6, l = t & 63;
  const int l15 = l & 15, l4 = l >> 4;

  // ===== attention scores S0 = Sln @ Qln^T (once; S0 stays resident) =====
  {
    f32x4 acc4[4];
    #pragma unroll
    for (int i = 0; i < 4; i++){ acc4[i][0]=0.f; acc4[i][1]=0.f; acc4[i][2]=0.f; acc4[i][3]=0.f; }
    const u16* Sa = Sh + (w*16+l15)*256 + l4*8;
    const u16* Sb = Sl + (w*16+l15)*256 + l4*8;
    short8v ah = *(const short8v*)Sa;
    short8v al = *(const short8v*)Sb;
    short8v bh[4], bl[4];
    #pragma unroll
    for (int nt = 0; nt < 4; nt++){
      bh[nt] = *(const short8v*)(Qh + (nt*16+l15)*256 + l4*8);
      bl[nt] = *(const short8v*)(Ql + (nt*16+l15)*256 + l4*8);
    }
    #pragma unroll
    for (int ch = 0; ch < 8; ch++){
      short8v nah, nal, nbh[4], nbl[4];
      if (ch < 7){
        nah = *(const short8v*)(Sa + (ch+1)*32);
        nal = *(const short8v*)(Sb + (ch+1)*32);
        #pragma unroll
        for (int nt = 0; nt < 4; nt++){
          nbh[nt] = *(const short8v*)(Qh + (nt*16+l15)*256 + (ch+1)*32 + l4*8);
          nbl[nt] = *(const short8v*)(Ql + (nt*16+l15)*256 + (ch+1)*32 + l4*8);
        }
      }
      #pragma unroll
      for (int nt = 0; nt < 4; nt++){
        MFMA(acc4[nt], ah, bh[nt]);
        MFMA(acc4[nt], ah, bl[nt]);
        MFMA(acc4[nt], al, bh[nt]);
      }
      if (ch < 7){
        ah = nah; al = nal;
        #pragma unroll
        for (int nt = 0; nt < 4; nt++){ bh[nt] = nbh[nt]; bl[nt] = nbl[nt]; }
      }
    }
    #pragma unroll
    for (int nt = 0; nt < 4; nt++)
      #pragma unroll
      for (int r = 0; r < 4; r++)
        S0[(w*16 + l4*4 + r)*68 + nt*16 + l15] = acc4[nt][r];
    __syncthreads();
  }

  // ===== softmax: fp32 from S0, write P packed hi|lo =====
  auto softmax_row = [&](){
    if (t < 64){
      float mxv = -1e30f, sm = 0.f;
      for (int k = 0; k < 64; k++) mxv = fmaxf(mxv, S0[t*68 + k]);
      for (int k = 0; k < 64; k++) sm += __expf(S0[t*68 + k] - mxv);
      smx[t] = mxv; smi[t] = 1.f/sm;
    }
    __syncthreads();
    #pragma unroll
    for (int r = 0; r < 16; r++){
      int idx = t + 256*r, ll = idx >> 6, k = idx & 63;
      P[ll*68 + k] = pack_split(__expf(S0[ll*68 + k] - smx[ll]) * smi[ll]);
    }
    __syncthreads();
  };
  auto softmax_col_T = [&](){
    if (t < 64){
      float mxv = -1e30f, sm = 0.f;
      for (int ld = 0; ld < 64; ld++) mxv = fmaxf(mxv, S0[ld*68 + t]);
      for (int ld = 0; ld < 64; ld++) sm += __expf(S0[ld*68 + t] - mxv);
      smx[t] = mxv; smi[t] = 1.f/sm;
    }
    __syncthreads();
    #pragma unroll
    for (int r = 0; r < 16; r++){         // read S0, write P (disjoint) — no race
      int idx = t + 256*r, ll = idx >> 6, k = idx & 63;
      P[k*68 + ll] = pack_split(__expf(S0[ll*68 + k] - smx[k]) * smi[k]);
    }
    __syncthreads();
  };

  // ===== one side: 1 barrier per ch, acc init from XP =====
  auto do_side = [&](const u16* Xh, const u16* Xl, const u16* Oh, const u16* Ol,
                     const float* xp, int cat_off){
    const int Mg = w >> 1, Ng = w & 1;
    f32x4 acc[2][8];
    #pragma unroll
    for (int mt = 0; mt < 2; mt++)
      #pragma unroll
      for (int nt = 0; nt < 8; nt++){
        const float* xr = xp + (Mg*32 + mt*16 + l4*4)*256 + Ng*128 + nt*16 + l15;
        acc[mt][nt][0] = xr[0];
        acc[mt][nt][1] = xr[256];
        acc[mt][nt][2] = xr[512];
        acc[mt][nt][3] = xr[768];
      }

    // ---- prime: OcT ch0 (load+write buf0), issue OcT ch1 loads ----
    short8v svh = *(const short8v*)(Oh + l*256 + w*8);
    short8v svl = *(const short8v*)(Ol + l*256 + w*8);
    #pragma unroll
    for (int e = 0; e < 8; e++){
      OcT[(w*8+e)*80 + l]        = (u16)svh[e];
      OcT[2560 + (w*8+e)*80 + l] = (u16)svl[e];
    }
    svh = *(const short8v*)(Oh + l*256 + 32 + w*8);
    svl = *(const short8v*)(Ol + l*256 + 32 + w*8);
    __syncthreads();                     // OcT[0] visible

    const int xoff = (Mg*32 + l15)*256 + l4*8;

    #pragma unroll 1
    for (int ch = 0; ch < 8; ch++){
      // ---- issue X loads + first proj-W batch (consumed after barrier) ----
      short8v xh0 = *(const short8v*)(Xh + xoff + ch*32);
      short8v xl0 = *(const short8v*)(Xl + xoff + ch*32);
      short8v xh1 = *(const short8v*)(Xh + xoff + 4096 + ch*32);
      short8v xl1 = *(const short8v*)(Xl + xoff + 4096 + ch*32);
      short8v wa[8], wb[8];
      WLH(wa, 1, 0);                     // L2 latency hides under AO MFMAs

      // ---- AO chunk = P @ O from OcT[ch&1] -> AOc[ch&1] ----
      {
        const u16* Ob = OcT + (ch&1)*5120;
        f32x4 ao0 = {0.f,0.f,0.f,0.f}, ao1 = {0.f,0.f,0.f,0.f};
        #pragma unroll
        for (int ks = 0; ks < 2; ks++){
          const u32* pp = P + (w*16 + l15)*68 + ks*32 + l4*8;
          uint4 q0 = *(const uint4*)pp;
          uint4 q1 = *(const uint4*)(pp + 4);
          short8v ph, pl; unpack8(q0, q1, ph, pl);
          const u16* ob0 = Ob + l15*80 + ks*32 + l4*8;
          const u16* ob1 = Ob + (16 + l15)*80 + ks*32 + l4*8;
          short8v bh0 = *(const short8v*)ob0;
          short8v bl0 = *(const short8v*)(ob0 + 2560);
          short8v bh1 = *(const short8v*)ob1;
          short8v bl1 = *(const short8v*)(ob1 + 2560);
          MFMA(ao0, ph, bh0); MFMA(ao0, ph, bl0); MFMA(ao0, pl, bh0);
          MFMA(ao1, ph, bh1); MFMA(ao1, ph, bl1); MFMA(ao1, pl, bh1);
        }
        float* Ad = AOc + (ch&1)*2304;
        #pragma unroll
        for (int r = 0; r < 4; r++){
          Ad[(w*16 + l4*4 + r)*36 + l15]      = ao0[r];
          Ad[(w*16 + l4*4 + r)*36 + 16 + l15] = ao1[r];
        }
      }

      // ---- stage OcT[(ch+1)&1] from regs (pre-barrier); issue ch+2 O loads ----
      if (ch < 7){
        u16* Ob1 = OcT + ((ch+1)&1)*5120;
        #pragma unroll
        for (int e = 0; e < 8; e++){
          Ob1[(w*8+e)*80 + l]        = (u16)svh[e];
          Ob1[2560 + (w*8+e)*80 + l] = (u16)svl[e];
        }
      }
      if (ch < 6){
        svh = *(const short8v*)(Oh + l*256 + (ch+2)*32 + w*8);
        svl = *(const short8v*)(Ol + l*256 + (ch+2)*32 + w*8);
      }
      __syncthreads();                   // single barrier: AOc[ch&1]+OcT[(ch+1)&1] visible

      // ---- build feature groups (a, |x-a|, x*a) from AOc[ch&1] ----
      short8v fh[3][2], fl[3][2];
      {
        const float* Ad = AOc + (ch&1)*2304;
        f32x4 xv0[2], xv1[2], av0[2], av1[2];
        #pragma unroll
        for (int mt_ = 0; mt_ < 2; mt_++){
          short8v xh = mt_ ? xh1 : xh0;
          short8v xl = mt_ ? xl1 : xl0;
          #pragma unroll
          for (int e_ = 0; e_ < 4; e_++){
            xv0[mt_][e_] = bf2f((u16)xh[e_])     + bf2f((u16)xl[e_]);
            xv1[mt_][e_] = bf2f((u16)xh[4 + e_]) + bf2f((u16)xl[4 + e_]);
          }
          const int row = Mg*32 + mt_*16 + l15;
          av0[mt_] = *(const f32x4*)(Ad + row*36 + l4*8);
          av1[mt_] = *(const f32x4*)(Ad + row*36 + l4*8 + 4);
        }
        #pragma unroll
        for (int mt_ = 0; mt_ < 2; mt_++){
          split8v(av0[mt_], av1[mt_], fh[0][mt_], fl[0][mt_]);
          f32x4 d0, d1, p0, p1;
          #pragma unroll
          for (int e_ = 0; e_ < 4; e_++){
            d0[e_] = fabsf(xv0[mt_][e_] - av0[mt_][e_]);
            d1[e_] = fabsf(xv1[mt_][e_] - av1[mt_][e_]);
            p0[e_] = xv0[mt_][e_] * av0[mt_][e_];
            p1[e_] = xv1[mt_][e_] * av1[mt_][e_];
          }
          split8v(d0, d1, fh[1][mt_], fl[1][mt_]);
          split8v(p0, p1, fh[2][mt_], fl[2][mt_]);
        }
      }

      // ---- proj: 6 half-group stages (wa preloaded), double-buffered W ----
      WLH(wb, 1, 1);
      WMH(wa, 0, 0);
      WLH(wa, 2, 0);
      WMH(wb, 0, 1);
      WLH(wb, 2, 1);
      WMH(wa, 1, 0);
      WLH(wa, 3, 0);
      WMH(wb, 1, 1);
      WLH(wb, 3, 1);
      WMH(wa, 2, 0);
      WMH(wb, 2, 1);
    }

    // ---- bias+mish+pool (max & mean over 64 rows) ----
    float* pmax2 = (float*)P;            // P dead -> [2 Mgroups][256]
    float* psum2 = pmax2 + 512;
    #pragma unroll
    for (int nt = 0; nt < 8; nt++){
      const int col = Ng*128 + nt*16 + l15;
      const float pb = pbias[col];
      float mx = -1e30f, sm = 0.f;
      #pragma unroll
      for (int mt_ = 0; mt_ < 2; mt_++)
        #pragma unroll
        for (int r = 0; r < 4; r++){
          float v = mishf(acc[mt_][nt][r] + pb);
          mx = fmaxf(mx, v); sm += v;
        }
      mx = fmaxf(mx, __shfl_xor(mx, 16, 64));
      mx = fmaxf(mx, __shfl_xor(mx, 32, 64));
      sm += __shfl_xor(sm, 16, 64);
      sm += __shfl_xor(sm, 32, 64);
      if (l4 == 0){ pmax2[Mg*256 + col] = mx; psum2[Mg*256 + col] = sm; }
    }
    __syncthreads();
    // ---- LN2 over 512 [max|mean] -> cat ----
    float v1 = fmaxf(pmax2[t], pmax2[256 + t]);
    float v2 = (psum2[t] + psum2[256 + t]) * (1.f/64.f);
    float p1 = wave_sum(v1 + v2);
    float p2 = wave_sum(v1*v1 + v2*v2);
    if (l == 0){ red[w] = p1; red[4 + w] = p2; }
    __syncthreads();
    if (t == 0){
      float s1 = red[0]+red[1]+red[2]+red[3];
      float s2 = red[4]+red[5]+red[6]+red[7];
      float mu  = s1 * (1.f/512.f);
      float var = s2 * (1.f/512.f) - mu*mu;
      stat[0] = mu; stat[1] = 1.f/sqrtf(var + LN_EPS);
    }
    __syncthreads();
    float mu = stat[0], rstd = stat[1];
    cat[cat_off + t]       = (v1 - mu)*rstd*ln2g[t]       + ln2b[t];
    cat[cat_off + 256 + t] = (v2 - mu)*rstd*ln2g[256 + t] + ln2b[256 + t];
    __syncthreads();
  };

  // ===== side S: P = rowSoftmax; x = s, other = q =====
  softmax_row();
  do_side(Sh, Sl, Qh, Ql, xpS, 512);
  // ===== side Q: P = colSoftmax^T (S0 still resident); x = q, other = s =====
  softmax_col_T();
  do_side(Qh, Ql, Sh, Sl, xpQ, 0);

  // ===== MLP (fp32, coalesced k-major W1) =====
  {
    float acc1 = 0.f;
    const float* wt = W1T2 + t*4;
    #pragma unroll 8
    for (int kb = 0; kb < 256; kb++){
      float4 wv = *(const float4*)(wt + kb*1024);
      const float* cp = &cat[kb*4];
      acc1 += cp[0]*wv.x + cp[1]*wv.y + cp[2]*wv.z + cp[3]*wv.w;
    }
    float hv = mishf(acc1 + b1[t]);
    float contrib = wave_sum(hv * W2[t]);
    if (l == 0) mred[w] = contrib;
  }
  __syncthreads();
  if (t == 0){
    float hh = mred[0] + mred[1] + mred[2] + mred[3] + b2[0];
    logits[m] = mishf(hh)*W3[0] + b3[0];
  }
}

// ---------- finalize (fp32 output) ----------
__global__ void k_final9(const float* __restrict__ logits, float* __restrict__ out){
  int t = threadIdx.x;                   // 128
  if (t < 100){
    float v[10];
    float mn = 1e30f;
    #pragma unroll
    for (int j = 0; j < 10; j++){ v[j] = logits[t*10 + j]; mn = fminf(mn, v[j]); }
    float best = -1e30f; int bi = 0;
    #pragma unroll
    for (int j = 0; j < 10; j++){ if (v[j] > best){ best = v[j]; bi = j; } }
    #pragma unroll
    for (int j = 0; j < 10; j++) out[t*11 + j] = v[j];
    out[t*11 + 10] = mn - 1.f;
    out[1100 + t] = (float)bi;
  }
}

// ---------- launcher ----------
extern "C" void kernel_launch(void* const* d_in, const int* in_sizes, int n_in,
                              void* d_out, int out_size, void* d_ws, size_t ws_size,
                              hipStream_t stream){
  (void)in_sizes; (void)n_in; (void)out_size; (void)ws_size;
  const float* support = (const float*)d_in[0];
  const float* query   = (const float*)d_in[1];
  const float* ln_g    = (const float*)d_in[2];
  const float* ln_b    = (const float*)d_in[3];
  const float* ln2_g   = (const float*)d_in[4];
  const float* ln2_b   = (const float*)d_in[5];
  const float* proj_W  = (const float*)d_in[6];
  const float* proj_b  = (const float*)d_in[7];
  const float* W1      = (const float*)d_in[8];
  const float* b1      = (const float*)d_in[9];
  const float* W2      = (const float*)d_in[10];
  const float* b2      = (const float*)d_in[11];
  const float* W3      = (const float*)d_in[12];
  const float* b3      = (const float*)d_in[13];

  // workspace layout (~17.1 MB):
  char* wsb = (char*)d_ws;
  float* logits = (float*)wsb;                           // 4 KB
  u16* SHI = (u16*)(wsb + 4096);                         // 20*16384*2  = 640 KB
  u16* SLO = SHI + (size_t)20*16384;
  u16* QHI = SLO + (size_t)20*16384;                     // 100*16384*2 = 3.2 MB
  u16* QLO = QHI + (size_t)100*16384;
  u16* WHI = QLO + (size_t)100*16384;                    // 512 KB (frag order)
  u16* WLO = WHI + (size_t)262144;
  float* XPS  = (float*)(WLO + (size_t)262144);          // 20*16384*4  = 1.31 MB
  float* XPQ  = XPS + (size_t)20*16384;                  // 100*16384*4 = 6.55 MB
  float* W1T2 = XPQ + (size_t)100*16384;                 // 1 MB

  k_setup_A<<<dim3(504), dim3(256), 0, stream>>>(support, query, ln_g, ln_b,
                                                 proj_W, W1,
                                                 SHI, SLO, QHI, QLO, WHI, WLO,
                                                 W1T2);
  k_setup_xp<<<dim3(120), dim3(256), 0, stream>>>(SHI, SLO, QHI, QLO, WHI, WLO,
                                                  XPS, XPQ);
  k_pair15<<<dim3(1000), dim3(256), 0, stream>>>(SHI, SLO, QHI, QLO, WHI, WLO,
                                                 XPS, XPQ, W1T2,
                                                 proj_b, ln2_g, ln2_b,
                                                 b1, W2, b2, W3, b3, logits);
  k_final9<<<dim3(1), dim3(128), 0, stream>>>(logits, (float*)d_out);
}